// Round 3
// baseline (739.682 us; speedup 1.0000x reference)
//
#include <hip/hip_runtime.h>

#define Bn  4
#define Hn  256
#define Wn  256
#define Cn  16
#define NTn 9
#define HWn (Hn*Wn)
#define KF  129      // W/2 + 1
#define PI_F 3.14159265358979323846f

// ---------------------------------------------------------------------------
// Twiddle table: tw[m] = {cos(2*pi*m/256), -sin(2*pi*m/256)}, m = 0..127.
// Built once per block into LDS. Stage st uses tw[pos << (7-st)].
// ---------------------------------------------------------------------------
__device__ __forceinline__ void build_tw(float2* tw, int tid, int nthreads) {
  for (int m = tid; m < 128; m += nthreads) {
    float th = -2.0f * PI_F * (float)m / 256.0f;
    float sw, cw;
    __sincosf(th, &sw, &cw);
    tw[m] = make_float2(cw, sw);
  }
}

// ---------------------------------------------------------------------------
// In-LDS radix-2 DIT FFT of length 256, executed by a 64-lane group.
// Data must be loaded bit-reversed. inv=false forward, true inverse (unscaled).
// ---------------------------------------------------------------------------
__device__ __forceinline__ void fft256_lds(float2* s, const float2* tw,
                                           int lane, bool inv) {
#pragma unroll
  for (int st = 0; st < 8; ++st) {
    __syncthreads();
    const int half = 1 << st;
#pragma unroll
    for (int r = 0; r < 2; ++r) {
      int bf  = lane + (r << 6);           // butterfly id 0..127
      int pos = bf & (half - 1);
      int i0  = ((bf >> st) << (st + 1)) + pos;
      int i1  = i0 + half;
      float2 w = tw[pos << (7 - st)];
      float wi = inv ? -w.y : w.y;
      float2 u = s[i0], v = s[i1];
      float vr = v.x * w.x - v.y * wi;
      float vi = v.x * wi + v.y * w.x;
      s[i0] = make_float2(u.x + vr, u.y + vi);
      s[i1] = make_float2(u.x - vr, u.y - vi);
    }
  }
  __syncthreads();
}

// ---------------------------------------------------------------------------
// Zero the norm accumulators (ws is poisoned 0xAA before every launch).
// ---------------------------------------------------------------------------
__global__ void k_zero(float* __restrict__ nx2, float* __restrict__ ny2) {
  int t = threadIdx.x;
  if (t < 64) nx2[t] = 0.f;
  for (int i = t; i < NTn * Bn * Cn; i += 256) ny2[i] = 0.f;
}

// ---------------------------------------------------------------------------
// Transpose (B,H,W,C) -> planar (B*C, H*W) for coalesced plane access.
// ---------------------------------------------------------------------------
__global__ void k_transpose(const float* __restrict__ inp, float* __restrict__ P) {
  __shared__ float tile[16][17];
  int g  = blockIdx.x * 16;                 // base pixel in flat b*HW space
  int px = threadIdx.x & 15, py = threadIdx.x >> 4;
  tile[py][px] = inp[(size_t)(g + py) * Cn + px];
  __syncthreads();
  int b = g / HWn, p0 = g - b * HWn;
  int c2 = threadIdx.x >> 4, p2 = threadIdx.x & 15;
  P[(size_t)(b * Cn + c2) * HWn + p0 + p2] = tile[p2][c2];
}

// ---------------------------------------------------------------------------
// Warp index map: idx[t, i*W+j] = yi*W+xi or -1 if out of bounds.
// ---------------------------------------------------------------------------
__global__ void k_idx(const float* __restrict__ T, int* __restrict__ idx) {
#pragma clang fp contract(off)
  int g = blockIdx.x * blockDim.x + threadIdx.x;
  if (g >= NTn * HWn) return;
  int t = g / HWn, pix = g - t * HWn;
  int i = pix >> 8, j = pix & 255;
  const float* a = T + t * 8;
  float x = (float)j, y = (float)i;
  float kk = a[6] * x + a[7] * y + 1.0f;
  float xf = (a[0] * x + a[1] * y + a[2]) / kk;
  float yf = (a[3] * x + a[4] * y + a[5]) / kk;
  float xr = rintf(xf), yr = rintf(yf);       // round-half-even, matches jnp.round
  bool valid = (xr >= 0.f) && (xr < (float)Wn) && (yr >= 0.f) && (yr < (float)Hn);
  idx[g] = valid ? ((int)yr * Wn + (int)xr) : -1;
}

// ---------------------------------------------------------------------------
// Row FFT of x + fused ||x||^2 accumulation.
// Store transposed: Fx[(b*C+c)][k][i]  (so column pass reads contiguously).
// ---------------------------------------------------------------------------
__global__ void k_xrow(const float* __restrict__ P, float2* __restrict__ Fx,
                       float* __restrict__ nx2) {
  __shared__ float2 sb[4][256];
  __shared__ float2 tw[128];
  build_tw(tw, threadIdx.x, 256);
  int grp = threadIdx.x >> 6, lane = threadIdx.x & 63;
  int item = blockIdx.x * 4 + grp;            // (b*C+c)*H + i
  float2* s = sb[grp];
  int plane = item >> 8, i = item & 255;
  const float* row = P + (size_t)plane * HWn + (size_t)i * Wn;
  float ss = 0.f;
#pragma unroll
  for (int q = 0; q < 4; ++q) {
    int j = lane + (q << 6);
    float v = row[j];
    ss += v * v;
    int rv = __brev((unsigned)j) >> 24;
    s[rv] = make_float2(v, 0.f);
  }
#pragma unroll
  for (int o = 32; o > 0; o >>= 1) ss += __shfl_down(ss, o, 64);
  if (lane == 0) atomicAdd(nx2 + plane, ss);
  fft256_lds(s, tw, lane, false);
  for (int k = lane; k < KF; k += 64)
    Fx[((size_t)plane * KF + k) * Hn + i] = s[k];
}

// ---------------------------------------------------------------------------
// Generic in-place FFT along the contiguous (last, length-256) axis.
// Used for: forward column FFT of Fx (inv=0), inverse column FFT of G (inv=1).
// ---------------------------------------------------------------------------
__global__ void k_colfft(float2* __restrict__ D, int nItems, int inv) {
  __shared__ float2 sb[4][256];
  __shared__ float2 tw[128];
  build_tw(tw, threadIdx.x, 256);
  int grp = threadIdx.x >> 6, lane = threadIdx.x & 63;
  int item = blockIdx.x * 4 + grp;
  bool act = item < nItems;
  float2* s = sb[grp];
  float2* Dp = D + (size_t)item * Hn;
  if (act) {
#pragma unroll
    for (int q = 0; q < 4; ++q) {
      int i = lane + (q << 6);
      int rv = __brev((unsigned)i) >> 24;
      s[rv] = Dp[i];
    }
  }
  fft256_lds(s, tw, lane, inv != 0);
  if (act) {
#pragma unroll
    for (int q = 0; q < 4; ++q) {
      int i = lane + (q << 6);
      Dp[i] = s[i];
    }
  }
}

// ---------------------------------------------------------------------------
// Row FFT of warped y for channel chunk [c0, c0+CC) + fused ||y||^2 accum.
// Y layout: [(t*B+b)*CC + cc][k][i]
// ---------------------------------------------------------------------------
__global__ void k_yrow(const float* __restrict__ P, const int* __restrict__ idx,
                       float2* __restrict__ Y, float* __restrict__ ny2,
                       int c0, int CC) {
  __shared__ float2 sb[4][256];
  __shared__ float2 tw[128];
  build_tw(tw, threadIdx.x, 256);
  int grp = threadIdx.x >> 6, lane = threadIdx.x & 63;
  int item = blockIdx.x * 4 + grp;            // ((t*B+b)*CC+cc)*H + i
  float2* s = sb[grp];
  int i = item & 255;
  int rem = item >> 8;                        // (t*B+b)*CC + cc
  int cc = rem % CC, tb = rem / CC;
  int b = tb % Bn, t = tb / Bn;
  const float* pl = P + (size_t)(b * Cn + c0 + cc) * HWn;
  const int* ix = idx + (size_t)t * HWn + (size_t)i * Wn;
  float ss = 0.f;
#pragma unroll
  for (int q = 0; q < 4; ++q) {
    int j = lane + (q << 6);
    int id = ix[j];
    float v = (id >= 0) ? pl[id] : 0.f;
    ss += v * v;
    int rv = __brev((unsigned)j) >> 24;
    s[rv] = make_float2(v, 0.f);
  }
#pragma unroll
  for (int o = 32; o > 0; o >>= 1) ss += __shfl_down(ss, o, 64);
  if (lane == 0) atomicAdd(ny2 + (size_t)(t * Bn + b) * Cn + c0 + cc, ss);
  fft256_lds(s, tw, lane, false);
  for (int k = lane; k < KF; k += 64)
    Y[((size_t)rem * KF + k) * Hn + i] = s[k];
}

// ---------------------------------------------------------------------------
// Column FFT of y + fused Fx*conj(Fy)*scale accumulation over channel chunk.
// One 64-thread block per (t,b,k). G layout: [t*B+b][k][r], r = row frequency.
// ---------------------------------------------------------------------------
__global__ void k_ycol(const float2* __restrict__ Y, const float2* __restrict__ Fx,
                       const float* __restrict__ nx2, const float* __restrict__ ny2,
                       float2* __restrict__ G, int c0, int CC) {
  __shared__ float2 sb[256];
  __shared__ float2 tw[128];
  build_tw(tw, threadIdx.x, 64);
  int lane = threadIdx.x;                     // block = 64
  int item = blockIdx.x;                      // (t*B+b)*KF + k
  int k = item % KF, tb = item / KF;
  int b = tb % Bn, t = tb / Bn;
  float2 acc[4];
  float2* Gp = G + ((size_t)tb * KF + k) * Hn;
  if (c0 == 0) {
#pragma unroll
    for (int q = 0; q < 4; ++q) acc[q] = make_float2(0.f, 0.f);
  } else {
#pragma unroll
    for (int q = 0; q < 4; ++q) acc[q] = Gp[lane + (q << 6)];
  }
  for (int cc = 0; cc < CC; ++cc) {
    int c = c0 + cc;
    const float2* Yp = Y + ((size_t)(tb * CC + cc) * KF + k) * Hn;
    __syncthreads();
#pragma unroll
    for (int q = 0; q < 4; ++q) {
      int i = lane + (q << 6);
      int rv = __brev((unsigned)i) >> 24;
      sb[rv] = Yp[i];
    }
    fft256_lds(sb, tw, lane, false);
    float nx = sqrtf(nx2[b * Cn + c]);
    float ny = sqrtf(ny2[(t * Bn + b) * Cn + c]);
    float sc = 1.0f / ((float)Cn * (nx * ny + 1e-12f));
    const float2* Fxp = Fx + ((size_t)(b * Cn + c) * KF + k) * Hn;
#pragma unroll
    for (int q = 0; q < 4; ++q) {
      int r = lane + (q << 6);
      float2 fy = sb[r];
      float2 fx = Fxp[r];
      acc[q].x += sc * (fx.x * fy.x + fx.y * fy.y);   // fx * conj(fy)
      acc[q].y += sc * (fx.y * fy.x - fx.x * fy.y);
    }
  }
#pragma unroll
  for (int q = 0; q < 4; ++q) Gp[lane + (q << 6)] = acc[q];
}

// ---------------------------------------------------------------------------
// Hermitian-extend over k, inverse FFT along width, scale, write out[b,i,j,t].
// ---------------------------------------------------------------------------
__global__ void k_irow(const float2* __restrict__ G, float* __restrict__ out) {
  __shared__ float2 sb[4][256];
  __shared__ float2 tw[128];
  build_tw(tw, threadIdx.x, 256);
  int grp = threadIdx.x >> 6, lane = threadIdx.x & 63;
  int item = blockIdx.x * 4 + grp;            // tb*H + i (i = spatial row)
  float2* s = sb[grp];
  int i = item & 255, tb = item >> 8;
  const float2* Gp = G + (size_t)tb * KF * Hn + i;
#pragma unroll
  for (int q = 0; q < 4; ++q) {
    int k = lane + (q << 6);
    float2 z;
    if (k <= 128) {
      z = Gp[(size_t)k * Hn];
    } else {
      float2 w = Gp[(size_t)(256 - k) * Hn];
      z = make_float2(w.x, -w.y);
    }
    int rv = __brev((unsigned)k) >> 24;
    s[rv] = z;
  }
  fft256_lds(s, tw, lane, true);
  int b = tb % Bn, t = tb / Bn;
  float* op = out + ((size_t)(b * Hn + i) * Wn) * NTn + t;
  const float scale = 1.0f / ((float)Hn * (float)Wn);
#pragma unroll
  for (int q = 0; q < 4; ++q) {
    int j = lane + (q << 6);
    op[(size_t)j * NTn] = s[j].x * scale;
  }
}

// ---------------------------------------------------------------------------
extern "C" void kernel_launch(void* const* d_in, const int* in_sizes, int n_in,
                              void* d_out, int out_size, void* d_ws, size_t ws_size,
                              hipStream_t stream) {
  const float* inp = (const float*)d_in[0];   // (B,H,W,C) f32
  const float* T   = (const float*)d_in[1];   // (NT,8) f32
  float* out = (float*)d_out;                 // (B,H,W,NT) f32
  char* ws = (char*)d_ws;

  // Channel chunk: CC=4 halves G accumulator round-trips and chunk launches,
  // but needs a bigger Y buffer. Pick at runtime from ws_size (deterministic).
  auto need = [](int CC) -> size_t {
    size_t sz = 0;
    sz += (size_t)Bn * Cn * HWn * sizeof(float);                 // P
    sz += (size_t)NTn * HWn * sizeof(int);                       // idx
    sz += 1024 * sizeof(float);                                  // nx2 + ny2
    sz += (size_t)Bn * Cn * KF * Hn * sizeof(float2);            // Fx
    sz += (size_t)NTn * Bn * KF * Hn * sizeof(float2);           // G
    sz += (size_t)NTn * Bn * CC * KF * Hn * sizeof(float2);      // Y
    return sz;
  };
  const int CC = (ws_size >= need(4)) ? 4 : 2;

  size_t off = 0;
  float* P   = (float*)(ws + off); off += (size_t)Bn * Cn * HWn * sizeof(float);
  int*   idx = (int*)  (ws + off); off += (size_t)NTn * HWn * sizeof(int);
  float* nx2 = (float*)(ws + off); off += 256 * sizeof(float);
  float* ny2 = (float*)(ws + off); off += 768 * sizeof(float);
  float2* Fx = (float2*)(ws + off); off += (size_t)Bn * Cn * KF * Hn * sizeof(float2);
  float2* G  = (float2*)(ws + off); off += (size_t)NTn * Bn * KF * Hn * sizeof(float2);
  float2* Y  = (float2*)(ws + off); off += (size_t)NTn * Bn * CC * KF * Hn * sizeof(float2);
  (void)off; (void)in_sizes; (void)n_in; (void)out_size;

  k_zero<<<1, 256, 0, stream>>>(nx2, ny2);
  k_transpose<<<Bn * HWn / 16, 256, 0, stream>>>(inp, P);
  k_idx<<<(NTn * HWn + 255) / 256, 256, 0, stream>>>(T, idx);
  k_xrow<<<Bn * Cn * Hn / 4, 256, 0, stream>>>(P, Fx, nx2);
  // Forward column FFT of Fx: Fx[plane][k][i] -> [plane][k][r]
  k_colfft<<<(Bn * Cn * KF + 3) / 4, 256, 0, stream>>>(Fx, Bn * Cn * KF, 0);

  for (int c0 = 0; c0 < Cn; c0 += CC) {
    k_yrow<<<NTn * Bn * CC * Hn / 4, 256, 0, stream>>>(P, idx, Y, ny2, c0, CC);
    k_ycol<<<NTn * Bn * KF, 64, 0, stream>>>(Y, Fx, nx2, ny2, G, c0, CC);
  }

  // Inverse column FFT of G (row-frequency -> spatial row), in place.
  k_colfft<<<(NTn * Bn * KF + 3) / 4, 256, 0, stream>>>(G, NTn * Bn * KF, 1);
  k_irow<<<NTn * Bn * Hn / 4, 256, 0, stream>>>(G, out);
}

// Round 4
// 678.791 us; speedup vs baseline: 1.0897x; 1.0897x over previous
//
#include <hip/hip_runtime.h>

#define Bn  4
#define Hn  256
#define Wn  256
#define Cn  16
#define NTn 9
#define HWn (Hn*Wn)
#define KF  129      // W/2 + 1
#define PI_F 3.14159265358979323846f

// ---------------------------------------------------------------------------
// XOR swizzle for the wave-private FFT scratch: spreads every access pattern
// of the radix-4 exchanges evenly over the 32 LDS banks (verified per-pattern).
// ---------------------------------------------------------------------------
__device__ __forceinline__ int swz(int i) { return i ^ ((i >> 4) & 15); }

// Drain DS queue + compiler memory barrier. Same-wave LDS ops are processed
// in order by HW; this guarantees write->read ordering without __syncthreads.
__device__ __forceinline__ void lds_fence() {
  __asm__ volatile("s_waitcnt lgkmcnt(0)" ::: "memory");
}

__device__ __forceinline__ float2 cmul(float2 a, float2 b) {
  return make_float2(a.x*b.x - a.y*b.y, a.x*b.y + a.y*b.x);
}

// Radix-4 butterfly. Forward: X1 = y1 - i*y3, X3 = y1 + i*y3 (W4 = -i).
template<bool INV>
__device__ __forceinline__ void radix4(float2& x0, float2& x1, float2& x2, float2& x3) {
  float2 y0 = make_float2(x0.x + x2.x, x0.y + x2.y);
  float2 y1 = make_float2(x0.x - x2.x, x0.y - x2.y);
  float2 y2 = make_float2(x1.x + x3.x, x1.y + x3.y);
  float2 y3 = make_float2(x1.x - x3.x, x1.y - x3.y);
  x0 = make_float2(y0.x + y2.x, y0.y + y2.y);
  x2 = make_float2(y0.x - y2.x, y0.y - y2.y);
  if (!INV) {
    x1 = make_float2(y1.x + y3.y, y1.y - y3.x);   // y1 - i*y3
    x3 = make_float2(y1.x - y3.y, y1.y + y3.x);   // y1 + i*y3
  } else {
    x1 = make_float2(y1.x - y3.y, y1.y + y3.x);   // y1 + i*y3
    x3 = make_float2(y1.x + y3.y, y1.y - y3.x);   // y1 - i*y3
  }
}

struct Tw { float2 a1,a2,a3,b1,b2,b3,c1,c2,c3; };

// All twiddles are lane-only constants: W_256^l, W_64^(l&15), W_16^(l&3).
template<bool INV>
__device__ __forceinline__ Tw make_tw(int lane) {
  const float sgn = INV ? 2.0f * PI_F : -2.0f * PI_F;
  Tw t; float sw, cw;
  __sincosf(sgn * (float)lane / 256.0f, &sw, &cw);
  t.a1 = make_float2(cw, sw); t.a2 = cmul(t.a1, t.a1); t.a3 = cmul(t.a2, t.a1);
  __sincosf(sgn * (float)(lane & 15) / 64.0f, &sw, &cw);
  t.b1 = make_float2(cw, sw); t.b2 = cmul(t.b1, t.b1); t.b3 = cmul(t.b2, t.b1);
  __sincosf(sgn * (float)(lane & 3) / 16.0f, &sw, &cw);
  t.c1 = make_float2(cw, sw); t.c2 = cmul(t.c1, t.c1); t.c3 = cmul(t.c2, t.c1);
  return t;
}

// ---------------------------------------------------------------------------
// Per-wave FFT-256, radix-4 DIF. Input: v[a] = x[lane + 64a] (natural order).
// Output: natural-order spectrum in wave-private scratch s (read via swz()).
// No __syncthreads. s = 256 float2 (2 KB), private to this wave.
// ---------------------------------------------------------------------------
template<bool INV>
__device__ __forceinline__ void fft256(float2 v[4], float2* s, int lane, const Tw& t) {
  // stage 1: combine n, n+64, n+128, n+192 (lane-local)
  radix4<INV>(v[0], v[1], v[2], v[3]);
  v[1] = cmul(v[1], t.a1); v[2] = cmul(v[2], t.a2); v[3] = cmul(v[3], t.a3);
  s[swz(lane)]       = v[0];
  s[swz(lane + 64)]  = v[1];
  s[swz(lane + 128)] = v[2];
  s[swz(lane + 192)] = v[3];
  lds_fence();
  { int base = (lane >> 4) * 64 + (lane & 15);
    v[0] = s[swz(base)]; v[1] = s[swz(base + 16)];
    v[2] = s[swz(base + 32)]; v[3] = s[swz(base + 48)]; }
  lds_fence();
  // stage 2: FFT-64 (per subband j1 = lane>>4), twiddle base m = lane&15
  radix4<INV>(v[0], v[1], v[2], v[3]);
  v[1] = cmul(v[1], t.b1); v[2] = cmul(v[2], t.b2); v[3] = cmul(v[3], t.b3);
  { int base = (lane >> 4) * 64 + (lane & 15);
    s[swz(base)]      = v[0];
    s[swz(base + 16)] = v[1];
    s[swz(base + 32)] = v[2];
    s[swz(base + 48)] = v[3]; }
  lds_fence();
  { int base = (lane >> 4) * 64 + ((lane >> 2) & 3) * 16 + (lane & 3);
    v[0] = s[swz(base)]; v[1] = s[swz(base + 4)];
    v[2] = s[swz(base + 8)]; v[3] = s[swz(base + 12)]; }
  lds_fence();
  // stage 3: FFT-16, twiddle base qb = lane&3
  radix4<INV>(v[0], v[1], v[2], v[3]);
  v[1] = cmul(v[1], t.c1); v[2] = cmul(v[2], t.c2); v[3] = cmul(v[3], t.c3);
  { int base = (lane & ~3) * 4 + (lane & 3);
    s[swz(base)]      = v[0];
    s[swz(base + 4)]  = v[1];
    s[swz(base + 8)]  = v[2];
    s[swz(base + 12)] = v[3]; }
  lds_fence();
  { int base = lane * 4;
    v[0] = s[swz(base)]; v[1] = s[swz(base + 1)];
    v[2] = s[swz(base + 2)]; v[3] = s[swz(base + 3)]; }
  lds_fence();
  // stage 4: FFT-4, no twiddle. Output k = 64*j4 + 16*j3 + 4*j2 + j1.
  radix4<INV>(v[0], v[1], v[2], v[3]);
  int dr = ((lane & 3) << 4) + (((lane >> 2) & 3) << 2) + (lane >> 4);
  s[swz(dr)]       = v[0];
  s[swz(dr + 64)]  = v[1];
  s[swz(dr + 128)] = v[2];
  s[swz(dr + 192)] = v[3];
  lds_fence();
}

// ---------------------------------------------------------------------------
__global__ void k_zero(float* __restrict__ nx2, float* __restrict__ ny2) {
  int t = threadIdx.x;
  if (t < 64) nx2[t] = 0.f;
  for (int i = t; i < NTn * Bn * Cn; i += 256) ny2[i] = 0.f;
}

__global__ void k_transpose(const float* __restrict__ inp, float* __restrict__ P) {
  __shared__ float tile[16][17];
  int g  = blockIdx.x * 16;
  int px = threadIdx.x & 15, py = threadIdx.x >> 4;
  tile[py][px] = inp[(size_t)(g + py) * Cn + px];
  __syncthreads();
  int b = g / HWn, p0 = g - b * HWn;
  int c2 = threadIdx.x >> 4, p2 = threadIdx.x & 15;
  P[(size_t)(b * Cn + c2) * HWn + p0 + p2] = tile[p2][c2];
}

__global__ void k_idx(const float* __restrict__ T, int* __restrict__ idx) {
#pragma clang fp contract(off)
  int g = blockIdx.x * blockDim.x + threadIdx.x;
  if (g >= NTn * HWn) return;
  int t = g / HWn, pix = g - t * HWn;
  int i = pix >> 8, j = pix & 255;
  const float* a = T + t * 8;
  float x = (float)j, y = (float)i;
  float kk = a[6] * x + a[7] * y + 1.0f;
  float xf = (a[0] * x + a[1] * y + a[2]) / kk;
  float yf = (a[3] * x + a[4] * y + a[5]) / kk;
  float xr = rintf(xf), yr = rintf(yf);
  bool valid = (xr >= 0.f) && (xr < (float)Wn) && (yr >= 0.f) && (yr < (float)Hn);
  idx[g] = valid ? ((int)yr * Wn + (int)xr) : -1;
}

// ---------------------------------------------------------------------------
// Row FFT of x + fused ||x||^2. One item (plane,row) per wave.
// ---------------------------------------------------------------------------
__global__ void k_xrow(const float* __restrict__ P, float2* __restrict__ Fx,
                       float* __restrict__ nx2) {
  __shared__ float2 sb[4][256];
  int w = threadIdx.x >> 6, lane = threadIdx.x & 63;
  float2* s = sb[w];
  Tw t = make_tw<false>(lane);
  int item = blockIdx.x * 4 + w;            // (b*C+c)*H + i
  int plane = item >> 8, i = item & 255;
  const float* row = P + (size_t)plane * HWn + (size_t)i * Wn;
  float2 v[4];
  float ss = 0.f;
#pragma unroll
  for (int q = 0; q < 4; ++q) {
    float x = row[lane + (q << 6)];
    ss += x * x;
    v[q] = make_float2(x, 0.f);
  }
#pragma unroll
  for (int o = 32; o > 0; o >>= 1) ss += __shfl_down(ss, o, 64);
  if (lane == 0) atomicAdd(nx2 + plane, ss);
  fft256<false>(v, s, lane, t);
  for (int k = lane; k < KF; k += 64)
    Fx[((size_t)plane * KF + k) * Hn + i] = s[swz(k)];
}

// ---------------------------------------------------------------------------
// In-place FFT along the contiguous length-256 axis. One item per wave.
// ---------------------------------------------------------------------------
template<bool INV>
__global__ void k_colfft(float2* __restrict__ D) {
  __shared__ float2 sb[4][256];
  int w = threadIdx.x >> 6, lane = threadIdx.x & 63;
  float2* s = sb[w];
  Tw t = make_tw<INV>(lane);
  int item = blockIdx.x * 4 + w;
  float2* Dp = D + (size_t)item * Hn;
  float2 v[4];
#pragma unroll
  for (int q = 0; q < 4; ++q) v[q] = Dp[lane + (q << 6)];
  fft256<INV>(v, s, lane, t);
#pragma unroll
  for (int q = 0; q < 4; ++q) {
    int j = lane + (q << 6);
    Dp[j] = s[swz(j)];
  }
}

// ---------------------------------------------------------------------------
// Row FFT of warped y for channel chunk + fused ||y||^2. One item per wave.
// ---------------------------------------------------------------------------
__global__ void k_yrow(const float* __restrict__ P, const int* __restrict__ idx,
                       float2* __restrict__ Y, float* __restrict__ ny2,
                       int c0, int CC) {
  __shared__ float2 sb[4][256];
  int w = threadIdx.x >> 6, lane = threadIdx.x & 63;
  float2* s = sb[w];
  Tw t = make_tw<false>(lane);
  int item = blockIdx.x * 4 + w;            // ((t*B+b)*CC+cc)*H + i
  int i = item & 255;
  int rem = item >> 8;
  int cc = rem % CC, tb = rem / CC;
  int b = tb % Bn, tt = tb / Bn;
  const float* pl = P + (size_t)(b * Cn + c0 + cc) * HWn;
  const int* ix = idx + (size_t)tt * HWn + (size_t)i * Wn;
  float2 v[4];
  float ss = 0.f;
#pragma unroll
  for (int q = 0; q < 4; ++q) {
    int id = ix[lane + (q << 6)];
    float x = (id >= 0) ? pl[id] : 0.f;
    ss += x * x;
    v[q] = make_float2(x, 0.f);
  }
#pragma unroll
  for (int o = 32; o > 0; o >>= 1) ss += __shfl_down(ss, o, 64);
  if (lane == 0) atomicAdd(ny2 + (size_t)(tt * Bn + b) * Cn + c0 + cc, ss);
  fft256<false>(v, s, lane, t);
  for (int k = lane; k < KF; k += 64)
    Y[((size_t)rem * KF + k) * Hn + i] = s[swz(k)];
}

// ---------------------------------------------------------------------------
// Column FFT of y + fused Fx*conj(Fy)*scale accumulation. One (t,b,k) per wave.
// ---------------------------------------------------------------------------
__global__ void k_ycol(const float2* __restrict__ Y, const float2* __restrict__ Fx,
                       const float* __restrict__ nx2, const float* __restrict__ ny2,
                       float2* __restrict__ G, int c0, int CC) {
  __shared__ float2 sb[4][256];
  int w = threadIdx.x >> 6, lane = threadIdx.x & 63;
  float2* s = sb[w];
  Tw t = make_tw<false>(lane);
  int item = blockIdx.x * 4 + w;            // (t*B+b)*KF + k
  int k = item % KF, tb = item / KF;
  int b = tb % Bn, tt = tb / Bn;
  float2 acc[4];
  float2* Gp = G + ((size_t)tb * KF + k) * Hn;
  if (c0 == 0) {
#pragma unroll
    for (int q = 0; q < 4; ++q) acc[q] = make_float2(0.f, 0.f);
  } else {
#pragma unroll
    for (int q = 0; q < 4; ++q) acc[q] = Gp[lane + (q << 6)];
  }
  for (int cc = 0; cc < CC; ++cc) {
    int c = c0 + cc;
    const float2* Yp = Y + ((size_t)(tb * CC + cc) * KF + k) * Hn;
    float2 v[4];
#pragma unroll
    for (int q = 0; q < 4; ++q) v[q] = Yp[lane + (q << 6)];
    fft256<false>(v, s, lane, t);
    float nx = sqrtf(nx2[b * Cn + c]);
    float ny = sqrtf(ny2[(tt * Bn + b) * Cn + c]);
    float sc = 1.0f / ((float)Cn * (nx * ny + 1e-12f));
    const float2* Fxp = Fx + ((size_t)(b * Cn + c) * KF + k) * Hn;
#pragma unroll
    for (int q = 0; q < 4; ++q) {
      int r = lane + (q << 6);
      float2 fy = s[swz(r)];
      float2 fx = Fxp[r];
      acc[q].x += sc * (fx.x * fy.x + fx.y * fy.y);   // fx * conj(fy)
      acc[q].y += sc * (fx.y * fy.x - fx.x * fy.y);
    }
  }
#pragma unroll
  for (int q = 0; q < 4; ++q) Gp[lane + (q << 6)] = acc[q];
}

// ---------------------------------------------------------------------------
// Hermitian-extend over k, inverse FFT along width, scale, write out[b,i,j,t].
// ---------------------------------------------------------------------------
__global__ void k_irow(const float2* __restrict__ G, float* __restrict__ out) {
  __shared__ float2 sb[4][256];
  int w = threadIdx.x >> 6, lane = threadIdx.x & 63;
  float2* s = sb[w];
  Tw t = make_tw<true>(lane);
  int item = blockIdx.x * 4 + w;            // tb*H + i (spatial row)
  int i = item & 255, tb = item >> 8;
  const float2* Gp = G + (size_t)tb * KF * Hn + i;
  float2 v[4];
#pragma unroll
  for (int q = 0; q < 4; ++q) {
    int k = lane + (q << 6);
    if (k <= 128) {
      v[q] = Gp[(size_t)k * Hn];
    } else {
      float2 z = Gp[(size_t)(256 - k) * Hn];
      v[q] = make_float2(z.x, -z.y);
    }
  }
  fft256<true>(v, s, lane, t);
  int b = tb % Bn, tt = tb / Bn;
  float* op = out + ((size_t)(b * Hn + i) * Wn) * NTn + tt;
  const float scale = 1.0f / ((float)Hn * (float)Wn);
#pragma unroll
  for (int q = 0; q < 4; ++q) {
    int j = lane + (q << 6);
    op[(size_t)j * NTn] = s[swz(j)].x * scale;
  }
}

// ---------------------------------------------------------------------------
extern "C" void kernel_launch(void* const* d_in, const int* in_sizes, int n_in,
                              void* d_out, int out_size, void* d_ws, size_t ws_size,
                              hipStream_t stream) {
  const float* inp = (const float*)d_in[0];
  const float* T   = (const float*)d_in[1];
  float* out = (float*)d_out;
  char* ws = (char*)d_ws;

  auto need = [](int CC) -> size_t {
    size_t sz = 0;
    sz += (size_t)Bn * Cn * HWn * sizeof(float);                 // P
    sz += (size_t)NTn * HWn * sizeof(int);                       // idx
    sz += 1024 * sizeof(float);                                  // nx2 + ny2
    sz += (size_t)Bn * Cn * KF * Hn * sizeof(float2);            // Fx
    sz += (size_t)NTn * Bn * KF * Hn * sizeof(float2);           // G
    sz += (size_t)NTn * Bn * CC * KF * Hn * sizeof(float2);      // Y
    return sz;
  };
  const int CC = (ws_size >= need(4)) ? 4 : 2;

  size_t off = 0;
  float* P   = (float*)(ws + off); off += (size_t)Bn * Cn * HWn * sizeof(float);
  int*   idx = (int*)  (ws + off); off += (size_t)NTn * HWn * sizeof(int);
  float* nx2 = (float*)(ws + off); off += 256 * sizeof(float);
  float* ny2 = (float*)(ws + off); off += 768 * sizeof(float);
  float2* Fx = (float2*)(ws + off); off += (size_t)Bn * Cn * KF * Hn * sizeof(float2);
  float2* G  = (float2*)(ws + off); off += (size_t)NTn * Bn * KF * Hn * sizeof(float2);
  float2* Y  = (float2*)(ws + off); off += (size_t)NTn * Bn * CC * KF * Hn * sizeof(float2);
  (void)off; (void)in_sizes; (void)n_in; (void)out_size;

  k_zero<<<1, 256, 0, stream>>>(nx2, ny2);
  k_transpose<<<Bn * HWn / 16, 256, 0, stream>>>(inp, P);
  k_idx<<<(NTn * HWn + 255) / 256, 256, 0, stream>>>(T, idx);
  k_xrow<<<Bn * Cn * Hn / 4, 256, 0, stream>>>(P, Fx, nx2);
  // Forward column FFT of Fx: Fx[plane][k][i] -> [plane][k][r]  (8256 items, %4==0)
  k_colfft<false><<<Bn * Cn * KF / 4, 256, 0, stream>>>(Fx);

  for (int c0 = 0; c0 < Cn; c0 += CC) {
    k_yrow<<<NTn * Bn * CC * Hn / 4, 256, 0, stream>>>(P, idx, Y, ny2, c0, CC);
    k_ycol<<<NTn * Bn * KF / 4, 256, 0, stream>>>(Y, Fx, nx2, ny2, G, c0, CC);
  }

  // Inverse column FFT of G (4644 items, %4==0), then final row inverse.
  k_colfft<true><<<NTn * Bn * KF / 4, 256, 0, stream>>>(G);
  k_irow<<<NTn * Bn * Hn / 4, 256, 0, stream>>>(G, out);
}

// Round 5
// 320.911 us; speedup vs baseline: 2.3049x; 2.1152x over previous
//
#include <hip/hip_runtime.h>

#define Bn  4
#define Hn  256
#define Wn  256
#define Cn  16
#define NTn 9
#define HWn (Hn*Wn)
#define KF  129      // W/2 + 1
#define PI_F 3.14159265358979323846f

// ---------------------------------------------------------------------------
// XOR swizzle for the wave-private FFT scratch (within a 256-entry row).
// ---------------------------------------------------------------------------
__device__ __forceinline__ int swz(int i) { return i ^ ((i >> 4) & 15); }

// Drain DS queue + compiler memory barrier (same-wave ordering, no barrier).
__device__ __forceinline__ void lds_fence() {
  __asm__ volatile("s_waitcnt lgkmcnt(0)" ::: "memory");
}

__device__ __forceinline__ float2 cmul(float2 a, float2 b) {
  return make_float2(a.x*b.x - a.y*b.y, a.x*b.y + a.y*b.x);
}

template<bool INV>
__device__ __forceinline__ void radix4(float2& x0, float2& x1, float2& x2, float2& x3) {
  float2 y0 = make_float2(x0.x + x2.x, x0.y + x2.y);
  float2 y1 = make_float2(x0.x - x2.x, x0.y - x2.y);
  float2 y2 = make_float2(x1.x + x3.x, x1.y + x3.y);
  float2 y3 = make_float2(x1.x - x3.x, x1.y - x3.y);
  x0 = make_float2(y0.x + y2.x, y0.y + y2.y);
  x2 = make_float2(y0.x - y2.x, y0.y - y2.y);
  if (!INV) {
    x1 = make_float2(y1.x + y3.y, y1.y - y3.x);   // y1 - i*y3
    x3 = make_float2(y1.x - y3.y, y1.y + y3.x);   // y1 + i*y3
  } else {
    x1 = make_float2(y1.x - y3.y, y1.y + y3.x);
    x3 = make_float2(y1.x + y3.y, y1.y - y3.x);
  }
}

struct Tw { float2 a1,a2,a3,b1,b2,b3,c1,c2,c3; };

template<bool INV>
__device__ __forceinline__ Tw make_tw(int lane) {
  const float sgn = INV ? 2.0f * PI_F : -2.0f * PI_F;
  Tw t; float sw, cw;
  __sincosf(sgn * (float)lane / 256.0f, &sw, &cw);
  t.a1 = make_float2(cw, sw); t.a2 = cmul(t.a1, t.a1); t.a3 = cmul(t.a2, t.a1);
  __sincosf(sgn * (float)(lane & 15) / 64.0f, &sw, &cw);
  t.b1 = make_float2(cw, sw); t.b2 = cmul(t.b1, t.b1); t.b3 = cmul(t.b2, t.b1);
  __sincosf(sgn * (float)(lane & 3) / 16.0f, &sw, &cw);
  t.c1 = make_float2(cw, sw); t.c2 = cmul(t.c1, t.c1); t.c3 = cmul(t.c2, t.c1);
  return t;
}

// ---------------------------------------------------------------------------
// Per-wave FFT-256, radix-4 DIF. Input v[a] = x[lane + 64a]; output natural-
// order spectrum in scratch row s (read via s[swz(k)]). No __syncthreads.
// ---------------------------------------------------------------------------
template<bool INV>
__device__ __forceinline__ void fft256(float2 v[4], float2* s, int lane, const Tw& t) {
  radix4<INV>(v[0], v[1], v[2], v[3]);
  v[1] = cmul(v[1], t.a1); v[2] = cmul(v[2], t.a2); v[3] = cmul(v[3], t.a3);
  s[swz(lane)]       = v[0];
  s[swz(lane + 64)]  = v[1];
  s[swz(lane + 128)] = v[2];
  s[swz(lane + 192)] = v[3];
  lds_fence();
  { int base = (lane >> 4) * 64 + (lane & 15);
    v[0] = s[swz(base)]; v[1] = s[swz(base + 16)];
    v[2] = s[swz(base + 32)]; v[3] = s[swz(base + 48)]; }
  lds_fence();
  radix4<INV>(v[0], v[1], v[2], v[3]);
  v[1] = cmul(v[1], t.b1); v[2] = cmul(v[2], t.b2); v[3] = cmul(v[3], t.b3);
  { int base = (lane >> 4) * 64 + (lane & 15);
    s[swz(base)]      = v[0];
    s[swz(base + 16)] = v[1];
    s[swz(base + 32)] = v[2];
    s[swz(base + 48)] = v[3]; }
  lds_fence();
  { int base = (lane >> 4) * 64 + ((lane >> 2) & 3) * 16 + (lane & 3);
    v[0] = s[swz(base)]; v[1] = s[swz(base + 4)];
    v[2] = s[swz(base + 8)]; v[3] = s[swz(base + 12)]; }
  lds_fence();
  radix4<INV>(v[0], v[1], v[2], v[3]);
  v[1] = cmul(v[1], t.c1); v[2] = cmul(v[2], t.c2); v[3] = cmul(v[3], t.c3);
  { int base = (lane & ~3) * 4 + (lane & 3);
    s[swz(base)]      = v[0];
    s[swz(base + 4)]  = v[1];
    s[swz(base + 8)]  = v[2];
    s[swz(base + 12)] = v[3]; }
  lds_fence();
  { int base = lane * 4;
    v[0] = s[swz(base)]; v[1] = s[swz(base + 1)];
    v[2] = s[swz(base + 2)]; v[3] = s[swz(base + 3)]; }
  lds_fence();
  radix4<INV>(v[0], v[1], v[2], v[3]);
  int dr = ((lane & 3) << 4) + (((lane >> 2) & 3) << 2) + (lane >> 4);
  s[swz(dr)]       = v[0];
  s[swz(dr + 64)]  = v[1];
  s[swz(dr + 128)] = v[2];
  s[swz(dr + 192)] = v[3];
  lds_fence();
}

// ---------------------------------------------------------------------------
__global__ void k_zero(float* __restrict__ nx2, float* __restrict__ ny2) {
  int t = threadIdx.x;
  if (t < 64) nx2[t] = 0.f;
  for (int i = t; i < NTn * Bn * Cn; i += 256) ny2[i] = 0.f;
}

__global__ void k_transpose(const float* __restrict__ inp, float* __restrict__ P) {
  __shared__ float tile[16][17];
  int g  = blockIdx.x * 16;
  int px = threadIdx.x & 15, py = threadIdx.x >> 4;
  tile[py][px] = inp[(size_t)(g + py) * Cn + px];
  __syncthreads();
  int b = g / HWn, p0 = g - b * HWn;
  int c2 = threadIdx.x >> 4, p2 = threadIdx.x & 15;
  P[(size_t)(b * Cn + c2) * HWn + p0 + p2] = tile[p2][c2];
}

__global__ void k_idx(const float* __restrict__ T, int* __restrict__ idx) {
#pragma clang fp contract(off)
  int g = blockIdx.x * blockDim.x + threadIdx.x;
  if (g >= NTn * HWn) return;
  int t = g / HWn, pix = g - t * HWn;
  int i = pix >> 8, j = pix & 255;
  const float* a = T + t * 8;
  float x = (float)j, y = (float)i;
  float kk = a[6] * x + a[7] * y + 1.0f;
  float xf = (a[0] * x + a[1] * y + a[2]) / kk;
  float yf = (a[3] * x + a[4] * y + a[5]) / kk;
  float xr = rintf(xf), yr = rintf(yf);
  bool valid = (xr >= 0.f) && (xr < (float)Wn) && (yr >= 0.f) && (yr < (float)Hn);
  idx[g] = valid ? ((int)yr * Wn + (int)xr) : -1;
}

// ---------------------------------------------------------------------------
// Row FFT of x, 8 rows per block (wave w does rows i0+w, i0+4+w).
// Block-cooperative coalesced store: 8 consecutive lanes write one full 64B
// line of Fx[plane][k][i0..i0+7].
// ---------------------------------------------------------------------------
__global__ void k_xrow(const float* __restrict__ P, float2* __restrict__ Fx,
                       float* __restrict__ nx2) {
  __shared__ float2 sb[8][264];
  __shared__ float red[4];
  int w = threadIdx.x >> 6, lane = threadIdx.x & 63;
  Tw t = make_tw<false>(lane);
  int plane = blockIdx.x >> 5;
  int i0 = (blockIdx.x & 31) << 3;
  const float* pb = P + (size_t)plane * HWn;
  float ssw = 0.f;
#pragma unroll
  for (int ff = 0; ff < 2; ++ff) {
    int ii = w + (ff << 2);
    const float* row = pb + (size_t)(i0 + ii) * Wn;
    float2 v[4];
#pragma unroll
    for (int q = 0; q < 4; ++q) {
      float x = row[lane + (q << 6)];
      ssw += x * x;
      v[q] = make_float2(x, 0.f);
    }
    fft256<false>(v, sb[ii], lane, t);
  }
#pragma unroll
  for (int o = 32; o > 0; o >>= 1) ssw += __shfl_down(ssw, o, 64);
  if (lane == 0) red[w] = ssw;
  __syncthreads();                       // also publishes sb across waves
  if (threadIdx.x == 0) atomicAdd(nx2 + plane, red[0] + red[1] + red[2] + red[3]);
  int ii = threadIdx.x & 7, kq = threadIdx.x >> 3;
  float2* Fp = Fx + (size_t)plane * KF * Hn + i0 + ii;
#pragma unroll
  for (int kk0 = 0; kk0 < 128; kk0 += 32) {
    int kk = kk0 + kq;
    Fp[(size_t)kk * Hn] = sb[ii][swz(kk)];
  }
  if (threadIdx.x < 8) Fp[(size_t)128 * Hn] = sb[ii][swz(128)];
}

// ---------------------------------------------------------------------------
// In-place FFT along the contiguous length-256 axis. One item per wave.
// ---------------------------------------------------------------------------
template<bool INV>
__global__ void k_colfft(float2* __restrict__ D) {
  __shared__ float2 sb[4][264];
  int w = threadIdx.x >> 6, lane = threadIdx.x & 63;
  float2* s = sb[w];
  Tw t = make_tw<INV>(lane);
  int item = blockIdx.x * 4 + w;
  float2* Dp = D + (size_t)item * Hn;
  float2 v[4];
#pragma unroll
  for (int q = 0; q < 4; ++q) v[q] = Dp[lane + (q << 6)];
  fft256<INV>(v, s, lane, t);
#pragma unroll
  for (int q = 0; q < 4; ++q) {
    int j = lane + (q << 6);
    Dp[j] = s[swz(j)];
  }
}

// ---------------------------------------------------------------------------
// Row FFT of warped y, 8 rows per block, coalesced transposed store of Y.
// ---------------------------------------------------------------------------
__global__ void k_yrow(const float* __restrict__ P, const int* __restrict__ idx,
                       float2* __restrict__ Y, float* __restrict__ ny2,
                       int c0, int CC) {
  __shared__ float2 sb[8][264];
  __shared__ float red[4];
  int w = threadIdx.x >> 6, lane = threadIdx.x & 63;
  Tw t = make_tw<false>(lane);
  int rem = blockIdx.x >> 5;              // (t*B+b)*CC + cc
  int i0 = (blockIdx.x & 31) << 3;
  int cc = rem % CC, tb = rem / CC;
  int b = tb % Bn, tt = tb / Bn;
  const float* pl = P + (size_t)(b * Cn + c0 + cc) * HWn;
  const int* ixb = idx + (size_t)tt * HWn;
  float ssw = 0.f;
#pragma unroll
  for (int ff = 0; ff < 2; ++ff) {
    int ii = w + (ff << 2);
    const int* ix = ixb + (size_t)(i0 + ii) * Wn;
    float2 v[4];
#pragma unroll
    for (int q = 0; q < 4; ++q) {
      int id = ix[lane + (q << 6)];
      float x = (id >= 0) ? pl[id] : 0.f;
      ssw += x * x;
      v[q] = make_float2(x, 0.f);
    }
    fft256<false>(v, sb[ii], lane, t);
  }
#pragma unroll
  for (int o = 32; o > 0; o >>= 1) ssw += __shfl_down(ssw, o, 64);
  if (lane == 0) red[w] = ssw;
  __syncthreads();
  if (threadIdx.x == 0)
    atomicAdd(ny2 + (size_t)(tt * Bn + b) * Cn + c0 + cc, red[0] + red[1] + red[2] + red[3]);
  int ii = threadIdx.x & 7, kq = threadIdx.x >> 3;
  float2* Yp = Y + (size_t)rem * KF * Hn + i0 + ii;
#pragma unroll
  for (int kk0 = 0; kk0 < 128; kk0 += 32) {
    int kk = kk0 + kq;
    Yp[(size_t)kk * Hn] = sb[ii][swz(kk)];
  }
  if (threadIdx.x < 8) Yp[(size_t)128 * Hn] = sb[ii][swz(128)];
}

// ---------------------------------------------------------------------------
// Column FFT of y + fused Fx*conj(Fy)*scale accumulation. One (t,b,k) per wave.
// All global accesses contiguous per wave.
// ---------------------------------------------------------------------------
__global__ void k_ycol(const float2* __restrict__ Y, const float2* __restrict__ Fx,
                       const float* __restrict__ nx2, const float* __restrict__ ny2,
                       float2* __restrict__ G, int c0, int CC) {
  __shared__ float2 sb[4][264];
  int w = threadIdx.x >> 6, lane = threadIdx.x & 63;
  float2* s = sb[w];
  Tw t = make_tw<false>(lane);
  int item = blockIdx.x * 4 + w;            // (t*B+b)*KF + k
  int k = item % KF, tb = item / KF;
  int b = tb % Bn, tt = tb / Bn;
  float2 acc[4];
  float2* Gp = G + ((size_t)tb * KF + k) * Hn;
  if (c0 == 0) {
#pragma unroll
    for (int q = 0; q < 4; ++q) acc[q] = make_float2(0.f, 0.f);
  } else {
#pragma unroll
    for (int q = 0; q < 4; ++q) acc[q] = Gp[lane + (q << 6)];
  }
  for (int cc = 0; cc < CC; ++cc) {
    int c = c0 + cc;
    const float2* Yp = Y + ((size_t)(tb * CC + cc) * KF + k) * Hn;
    float2 v[4];
#pragma unroll
    for (int q = 0; q < 4; ++q) v[q] = Yp[lane + (q << 6)];
    fft256<false>(v, s, lane, t);
    float nx = sqrtf(nx2[b * Cn + c]);
    float ny = sqrtf(ny2[(tt * Bn + b) * Cn + c]);
    float sc = 1.0f / ((float)Cn * (nx * ny + 1e-12f));
    const float2* Fxp = Fx + ((size_t)(b * Cn + c) * KF + k) * Hn;
#pragma unroll
    for (int q = 0; q < 4; ++q) {
      int r = lane + (q << 6);
      float2 fy = s[swz(r)];
      float2 fx = Fxp[r];
      acc[q].x += sc * (fx.x * fy.x + fx.y * fy.y);   // fx * conj(fy)
      acc[q].y += sc * (fx.y * fy.x - fx.x * fy.y);
    }
  }
#pragma unroll
  for (int q = 0; q < 4; ++q) Gp[lane + (q << 6)] = acc[q];
}

// ---------------------------------------------------------------------------
// Hermitian-extend + inverse row FFT, 8 spatial rows per block.
// Block-cooperative coalesced tile load of G (full 64B lines).
// ---------------------------------------------------------------------------
__global__ void k_irow(const float2* __restrict__ G, float* __restrict__ out) {
  __shared__ float2 t2[8][132];
  __shared__ float2 sb[4][264];
  int w = threadIdx.x >> 6, lane = threadIdx.x & 63;
  Tw t = make_tw<true>(lane);
  int tb = blockIdx.x >> 5;
  int i0 = (blockIdx.x & 31) << 3;
  {
    int ii = threadIdx.x & 7, kq = threadIdx.x >> 3;
    const float2* Gp = G + (size_t)tb * KF * Hn + i0 + ii;
#pragma unroll
    for (int kk0 = 0; kk0 < 128; kk0 += 32) {
      int kk = kk0 + kq;
      t2[ii][kk] = Gp[(size_t)kk * Hn];
    }
    if (threadIdx.x < 8) t2[ii][128] = Gp[(size_t)128 * Hn];
  }
  __syncthreads();
  int b = tb % Bn, tt = tb / Bn;
  const float scale = 1.0f / ((float)Hn * (float)Wn);
#pragma unroll
  for (int ff = 0; ff < 2; ++ff) {
    int ii = w + (ff << 2);
    int i = i0 + ii;
    float2 v[4];
#pragma unroll
    for (int q = 0; q < 4; ++q) {
      int k = lane + (q << 6);
      if (k <= 128) {
        v[q] = t2[ii][k];
      } else {
        float2 z = t2[ii][256 - k];
        v[q] = make_float2(z.x, -z.y);
      }
    }
    fft256<true>(v, sb[w], lane, t);
    float* op = out + ((size_t)(b * Hn + i) * Wn) * NTn + tt;
#pragma unroll
    for (int q = 0; q < 4; ++q) {
      int j = lane + (q << 6);
      op[(size_t)j * NTn] = sb[w][swz(j)].x * scale;
    }
  }
}

// ---------------------------------------------------------------------------
extern "C" void kernel_launch(void* const* d_in, const int* in_sizes, int n_in,
                              void* d_out, int out_size, void* d_ws, size_t ws_size,
                              hipStream_t stream) {
  const float* inp = (const float*)d_in[0];
  const float* T   = (const float*)d_in[1];
  float* out = (float*)d_out;
  char* ws = (char*)d_ws;

  auto need = [](int CC) -> size_t {
    size_t sz = 0;
    sz += (size_t)Bn * Cn * HWn * sizeof(float);                 // P
    sz += (size_t)NTn * HWn * sizeof(int);                       // idx
    sz += 1024 * sizeof(float);                                  // nx2 + ny2
    sz += (size_t)Bn * Cn * KF * Hn * sizeof(float2);            // Fx
    sz += (size_t)NTn * Bn * KF * Hn * sizeof(float2);           // G
    sz += (size_t)NTn * Bn * CC * KF * Hn * sizeof(float2);      // Y
    return sz;
  };
  const int CC = (ws_size >= need(4)) ? 4 : 2;

  size_t off = 0;
  float* P   = (float*)(ws + off); off += (size_t)Bn * Cn * HWn * sizeof(float);
  int*   idx = (int*)  (ws + off); off += (size_t)NTn * HWn * sizeof(int);
  float* nx2 = (float*)(ws + off); off += 256 * sizeof(float);
  float* ny2 = (float*)(ws + off); off += 768 * sizeof(float);
  float2* Fx = (float2*)(ws + off); off += (size_t)Bn * Cn * KF * Hn * sizeof(float2);
  float2* G  = (float2*)(ws + off); off += (size_t)NTn * Bn * KF * Hn * sizeof(float2);
  float2* Y  = (float2*)(ws + off); off += (size_t)NTn * Bn * CC * KF * Hn * sizeof(float2);
  (void)off; (void)in_sizes; (void)n_in; (void)out_size;

  k_zero<<<1, 256, 0, stream>>>(nx2, ny2);
  k_transpose<<<Bn * HWn / 16, 256, 0, stream>>>(inp, P);
  k_idx<<<(NTn * HWn + 255) / 256, 256, 0, stream>>>(T, idx);
  k_xrow<<<Bn * Cn * Hn / 8, 256, 0, stream>>>(P, Fx, nx2);
  // Forward column FFT of Fx: Fx[plane][k][i] -> [plane][k][r]
  k_colfft<false><<<Bn * Cn * KF / 4, 256, 0, stream>>>(Fx);

  for (int c0 = 0; c0 < Cn; c0 += CC) {
    k_yrow<<<NTn * Bn * CC * Hn / 8, 256, 0, stream>>>(P, idx, Y, ny2, c0, CC);
    k_ycol<<<NTn * Bn * KF / 4, 256, 0, stream>>>(Y, Fx, nx2, ny2, G, c0, CC);
  }

  // Inverse column FFT of G, then final row inverse + output.
  k_colfft<true><<<NTn * Bn * KF / 4, 256, 0, stream>>>(G);
  k_irow<<<NTn * Bn * Hn / 8, 256, 0, stream>>>(G, out);
}

// Round 6
// 274.551 us; speedup vs baseline: 2.6941x; 1.1689x over previous
//
#include <hip/hip_runtime.h>
#include <hip/hip_fp16.h>

#define Bn  4
#define Hn  256
#define Wn  256
#define Cn  16
#define NTn 9
#define HWn (Hn*Wn)
#define KF  129      // W/2 + 1
#define PI_F 3.14159265358979323846f

__device__ __forceinline__ int swz(int i) { return i ^ ((i >> 4) & 15); }

__device__ __forceinline__ void lds_fence() {
  __asm__ volatile("s_waitcnt lgkmcnt(0)" ::: "memory");
}

__device__ __forceinline__ float2 cmul(float2 a, float2 b) {
  return make_float2(a.x*b.x - a.y*b.y, a.x*b.y + a.y*b.x);
}

template<bool INV>
__device__ __forceinline__ void radix4(float2& x0, float2& x1, float2& x2, float2& x3) {
  float2 y0 = make_float2(x0.x + x2.x, x0.y + x2.y);
  float2 y1 = make_float2(x0.x - x2.x, x0.y - x2.y);
  float2 y2 = make_float2(x1.x + x3.x, x1.y + x3.y);
  float2 y3 = make_float2(x1.x - x3.x, x1.y - x3.y);
  x0 = make_float2(y0.x + y2.x, y0.y + y2.y);
  x2 = make_float2(y0.x - y2.x, y0.y - y2.y);
  if (!INV) {
    x1 = make_float2(y1.x + y3.y, y1.y - y3.x);   // y1 - i*y3
    x3 = make_float2(y1.x - y3.y, y1.y + y3.x);   // y1 + i*y3
  } else {
    x1 = make_float2(y1.x - y3.y, y1.y + y3.x);
    x3 = make_float2(y1.x + y3.y, y1.y - y3.x);
  }
}

struct Tw { float2 a1,a2,a3,b1,b2,b3,c1,c2,c3; };

template<bool INV>
__device__ __forceinline__ Tw make_tw(int lane) {
  const float sgn = INV ? 2.0f * PI_F : -2.0f * PI_F;
  Tw t; float sw, cw;
  __sincosf(sgn * (float)lane / 256.0f, &sw, &cw);
  t.a1 = make_float2(cw, sw); t.a2 = cmul(t.a1, t.a1); t.a3 = cmul(t.a2, t.a1);
  __sincosf(sgn * (float)(lane & 15) / 64.0f, &sw, &cw);
  t.b1 = make_float2(cw, sw); t.b2 = cmul(t.b1, t.b1); t.b3 = cmul(t.b2, t.b1);
  __sincosf(sgn * (float)(lane & 3) / 16.0f, &sw, &cw);
  t.c1 = make_float2(cw, sw); t.c2 = cmul(t.c1, t.c1); t.c3 = cmul(t.c2, t.c1);
  return t;
}

// Per-wave FFT-256, radix-4 DIF. Input v[a]=x[lane+64a]; natural-order output
// in scratch row s (read via s[swz(k)]). No __syncthreads (wave-private s).
template<bool INV>
__device__ __forceinline__ void fft256(float2 v[4], float2* s, int lane, const Tw& t) {
  radix4<INV>(v[0], v[1], v[2], v[3]);
  v[1] = cmul(v[1], t.a1); v[2] = cmul(v[2], t.a2); v[3] = cmul(v[3], t.a3);
  s[swz(lane)]       = v[0];
  s[swz(lane + 64)]  = v[1];
  s[swz(lane + 128)] = v[2];
  s[swz(lane + 192)] = v[3];
  lds_fence();
  { int base = (lane >> 4) * 64 + (lane & 15);
    v[0] = s[swz(base)]; v[1] = s[swz(base + 16)];
    v[2] = s[swz(base + 32)]; v[3] = s[swz(base + 48)]; }
  lds_fence();
  radix4<INV>(v[0], v[1], v[2], v[3]);
  v[1] = cmul(v[1], t.b1); v[2] = cmul(v[2], t.b2); v[3] = cmul(v[3], t.b3);
  { int base = (lane >> 4) * 64 + (lane & 15);
    s[swz(base)]      = v[0];
    s[swz(base + 16)] = v[1];
    s[swz(base + 32)] = v[2];
    s[swz(base + 48)] = v[3]; }
  lds_fence();
  { int base = (lane >> 4) * 64 + ((lane >> 2) & 3) * 16 + (lane & 3);
    v[0] = s[swz(base)]; v[1] = s[swz(base + 4)];
    v[2] = s[swz(base + 8)]; v[3] = s[swz(base + 12)]; }
  lds_fence();
  radix4<INV>(v[0], v[1], v[2], v[3]);
  v[1] = cmul(v[1], t.c1); v[2] = cmul(v[2], t.c2); v[3] = cmul(v[3], t.c3);
  { int base = (lane & ~3) * 4 + (lane & 3);
    s[swz(base)]      = v[0];
    s[swz(base + 4)]  = v[1];
    s[swz(base + 8)]  = v[2];
    s[swz(base + 12)] = v[3]; }
  lds_fence();
  { int base = lane * 4;
    v[0] = s[swz(base)]; v[1] = s[swz(base + 1)];
    v[2] = s[swz(base + 2)]; v[3] = s[swz(base + 3)]; }
  lds_fence();
  radix4<INV>(v[0], v[1], v[2], v[3]);
  int dr = ((lane & 3) << 4) + (((lane >> 2) & 3) << 2) + (lane >> 4);
  s[swz(dr)]       = v[0];
  s[swz(dr + 64)]  = v[1];
  s[swz(dr + 128)] = v[2];
  s[swz(dr + 192)] = v[3];
  lds_fence();
}

// ---------------------------------------------------------------------------
__global__ void k_transpose(const float* __restrict__ inp, float* __restrict__ P) {
  __shared__ float tile[16][17];
  int g  = blockIdx.x * 16;
  int px = threadIdx.x & 15, py = threadIdx.x >> 4;
  tile[py][px] = inp[(size_t)(g + py) * Cn + px];
  __syncthreads();
  int b = g / HWn, p0 = g - b * HWn;
  int c2 = threadIdx.x >> 4, p2 = threadIdx.x & 15;
  P[(size_t)(b * Cn + c2) * HWn + p0 + p2] = tile[p2][c2];
}

// Warp index map + zero-init of the norm accumulators (block 0).
__global__ void k_idx(const float* __restrict__ T, int* __restrict__ idx,
                      float* __restrict__ nx2, float* __restrict__ ny2) {
#pragma clang fp contract(off)
  if (blockIdx.x == 0) {
    if (threadIdx.x < 64) nx2[threadIdx.x] = 0.f;
    for (int i = threadIdx.x; i < NTn * Bn * Cn; i += 256) ny2[i] = 0.f;
  }
  int g = blockIdx.x * blockDim.x + threadIdx.x;
  if (g >= NTn * HWn) return;
  int t = g / HWn, pix = g - t * HWn;
  int i = pix >> 8, j = pix & 255;
  const float* a = T + t * 8;
  float x = (float)j, y = (float)i;
  float kk = a[6] * x + a[7] * y + 1.0f;
  float xf = (a[0] * x + a[1] * y + a[2]) / kk;
  float yf = (a[3] * x + a[4] * y + a[5]) / kk;
  float xr = rintf(xf), yr = rintf(yf);
  bool valid = (xr >= 0.f) && (xr < (float)Wn) && (yr >= 0.f) && (yr < (float)Hn);
  idx[g] = valid ? ((int)yr * Wn + (int)xr) : -1;
}

// ---------------------------------------------------------------------------
// Row FFT of x, 16 rows per block (wave w does rows ff*4+w), fused ||x||^2,
// coalesced half2 store: 16 consecutive lanes fill one 64B line of Fxh[k][i].
// ---------------------------------------------------------------------------
__global__ void k_xrow(const float* __restrict__ P, __half2* __restrict__ Fxh,
                       float* __restrict__ nx2) {
  __shared__ float2 sb[16][264];
  __shared__ float red[4];
  int w = threadIdx.x >> 6, lane = threadIdx.x & 63;
  Tw t = make_tw<false>(lane);
  int plane = blockIdx.x >> 4;
  int i0 = (blockIdx.x & 15) << 4;
  const float* pb = P + (size_t)plane * HWn;
  float ssw = 0.f;
#pragma unroll
  for (int ff = 0; ff < 4; ++ff) {
    int ii = (ff << 2) + w;
    const float* row = pb + (size_t)(i0 + ii) * Wn;
    float2 v[4];
#pragma unroll
    for (int q = 0; q < 4; ++q) {
      float x = row[lane + (q << 6)];
      ssw += x * x;
      v[q] = make_float2(x, 0.f);
    }
    fft256<false>(v, sb[ii], lane, t);
  }
#pragma unroll
  for (int o = 32; o > 0; o >>= 1) ssw += __shfl_down(ssw, o, 64);
  if (lane == 0) red[w] = ssw;
  __syncthreads();
  if (threadIdx.x == 0) atomicAdd(nx2 + plane, red[0] + red[1] + red[2] + red[3]);
  int ii = threadIdx.x & 15, kq = threadIdx.x >> 4;
  __half2* Fp = Fxh + (size_t)plane * KF * Hn + i0 + ii;
#pragma unroll
  for (int kk0 = 0; kk0 < 128; kk0 += 16) {
    int kk = kk0 + kq;
    Fp[(size_t)kk * Hn] = __float22half2_rn(sb[ii][swz(kk)]);
  }
  if (threadIdx.x < 16) Fp[(size_t)128 * Hn] = __float22half2_rn(sb[ii][swz(128)]);
}

// ---------------------------------------------------------------------------
// In-place forward FFT along the contiguous length-256 axis of a half2 array.
// ---------------------------------------------------------------------------
__global__ void k_colfft_h(__half2* __restrict__ D) {
  __shared__ float2 sb[4][264];
  int w = threadIdx.x >> 6, lane = threadIdx.x & 63;
  float2* s = sb[w];
  Tw t = make_tw<false>(lane);
  int item = blockIdx.x * 4 + w;
  __half2* Dp = D + (size_t)item * Hn;
  float2 v[4];
#pragma unroll
  for (int q = 0; q < 4; ++q) v[q] = __half22float2(Dp[lane + (q << 6)]);
  fft256<false>(v, s, lane, t);
#pragma unroll
  for (int q = 0; q < 4; ++q) {
    int j = lane + (q << 6);
    Dp[j] = __float22half2_rn(s[swz(j)]);
  }
}

// ---------------------------------------------------------------------------
// Row FFT of warped y, ALL channels, 16 rows per block, fused ||y||^2,
// coalesced half2 store into Yh[(t*B+b)*Cn + c][k][i].
// ---------------------------------------------------------------------------
__global__ void k_yrow(const float* __restrict__ P, const int* __restrict__ idx,
                       __half2* __restrict__ Yh, float* __restrict__ ny2) {
  __shared__ float2 sb[16][264];
  __shared__ float red[4];
  int w = threadIdx.x >> 6, lane = threadIdx.x & 63;
  Tw t = make_tw<false>(lane);
  int rem = blockIdx.x >> 4;              // (t*B+b)*Cn + c
  int i0 = (blockIdx.x & 15) << 4;
  int c = rem & 15, tb = rem >> 4;
  int b = tb & 3, tt = tb >> 2;
  const float* pl = P + (size_t)(b * Cn + c) * HWn;
  const int* ixb = idx + (size_t)tt * HWn;
  float ssw = 0.f;
#pragma unroll
  for (int ff = 0; ff < 4; ++ff) {
    int ii = (ff << 2) + w;
    const int* ix = ixb + (size_t)(i0 + ii) * Wn;
    float2 v[4];
#pragma unroll
    for (int q = 0; q < 4; ++q) {
      int id = ix[lane + (q << 6)];
      float x = (id >= 0) ? pl[id] : 0.f;
      ssw += x * x;
      v[q] = make_float2(x, 0.f);
    }
    fft256<false>(v, sb[ii], lane, t);
  }
#pragma unroll
  for (int o = 32; o > 0; o >>= 1) ssw += __shfl_down(ssw, o, 64);
  if (lane == 0) red[w] = ssw;
  __syncthreads();
  if (threadIdx.x == 0)
    atomicAdd(ny2 + rem, red[0] + red[1] + red[2] + red[3]);
  int ii = threadIdx.x & 15, kq = threadIdx.x >> 4;
  __half2* Yp = Yh + (size_t)rem * KF * Hn + i0 + ii;
#pragma unroll
  for (int kk0 = 0; kk0 < 128; kk0 += 16) {
    int kk = kk0 + kq;
    Yp[(size_t)kk * Hn] = __float22half2_rn(sb[ii][swz(kk)]);
  }
  if (threadIdx.x < 16) Yp[(size_t)128 * Hn] = __float22half2_rn(sb[ii][swz(128)]);
}

// ---------------------------------------------------------------------------
// Per (t,b,k): column FFT of y over all 16 channels + Fx*conj(Fy)*scale
// accumulation, then FUSED inverse FFT along the row-frequency axis.
// Writes G (fp32) exactly once. One wave per item, no barriers.
// ---------------------------------------------------------------------------
__global__ void k_ycol(const __half2* __restrict__ Yh, const __half2* __restrict__ Fxh,
                       const float* __restrict__ nx2, const float* __restrict__ ny2,
                       float2* __restrict__ G) {
  __shared__ float2 sb[4][264];
  int w = threadIdx.x >> 6, lane = threadIdx.x & 63;
  float2* s = sb[w];
  Tw tf = make_tw<false>(lane);
  int item = blockIdx.x * 4 + w;            // (t*B+b)*KF + k
  int k = item % KF, tb = item / KF;
  int b = tb & 3;
  float2 acc[4];
#pragma unroll
  for (int q = 0; q < 4; ++q) acc[q] = make_float2(0.f, 0.f);
  for (int c = 0; c < Cn; ++c) {
    const __half2* Yp = Yh + ((size_t)(tb * Cn + c) * KF + k) * Hn;
    float2 v[4];
#pragma unroll
    for (int q = 0; q < 4; ++q) v[q] = __half22float2(Yp[lane + (q << 6)]);
    fft256<false>(v, s, lane, tf);
    float nx = sqrtf(nx2[b * Cn + c]);
    float ny = sqrtf(ny2[tb * Cn + c]);
    float sc = 1.0f / ((float)Cn * (nx * ny + 1e-12f));
    const __half2* Fxp = Fxh + ((size_t)(b * Cn + c) * KF + k) * Hn;
#pragma unroll
    for (int q = 0; q < 4; ++q) {
      int r = lane + (q << 6);
      float2 fy = s[swz(r)];
      float2 fx = __half22float2(Fxp[r]);
      acc[q].x += sc * (fx.x * fy.x + fx.y * fy.y);   // fx * conj(fy)
      acc[q].y += sc * (fx.y * fy.x - fx.x * fy.y);
    }
  }
  // Fused inverse FFT along the row-frequency axis (was k_colfft<true>).
  Tw ti = make_tw<true>(lane);
  fft256<true>(acc, s, lane, ti);
  float2* Gp = G + (size_t)item * Hn;
#pragma unroll
  for (int q = 0; q < 4; ++q) {
    int j = lane + (q << 6);
    Gp[j] = s[swz(j)];
  }
}

// ---------------------------------------------------------------------------
// Final pass: block = (b, 4 spatial rows) x ALL 9 transforms.
// Hermitian-extend + inverse row FFT per t, assemble rowbuf[row][j*9+t] in
// LDS, then fully-contiguous 9216B-per-row store of out[b,i,j,t].
// ---------------------------------------------------------------------------
__global__ void k_irow(const float2* __restrict__ G, float* __restrict__ out) {
  __shared__ float2 tile[4][132];           // [ii][k] staging for one t
  __shared__ float rowbuf[4][Wn * NTn];     // [row][j*9+t]
  __shared__ float2 sb[4][264];
  int w = threadIdx.x >> 6, lane = threadIdx.x & 63;
  Tw ti = make_tw<true>(lane);
  int b = blockIdx.x >> 6;
  int i0 = (blockIdx.x & 63) << 2;
  const float scale = 1.0f / ((float)Hn * (float)Wn);
  for (int t = 0; t < NTn; ++t) {
    int tb = t * Bn + b;
    {
      int ii = threadIdx.x & 3, kq = threadIdx.x >> 2;   // 64 k's per pass
      const float2* Gp = G + (size_t)tb * KF * Hn + i0 + ii;
#pragma unroll
      for (int kk0 = 0; kk0 < 128; kk0 += 64) {
        int kk = kk0 + kq;
        tile[ii][kk] = Gp[(size_t)kk * Hn];
      }
      if (threadIdx.x < 4) tile[ii][128] = Gp[(size_t)128 * Hn];
    }
    __syncthreads();
    float2 v[4];
#pragma unroll
    for (int q = 0; q < 4; ++q) {
      int k = lane + (q << 6);
      if (k <= 128) {
        v[q] = tile[w][k];
      } else {
        float2 z = tile[w][256 - k];
        v[q] = make_float2(z.x, -z.y);
      }
    }
    fft256<true>(v, sb[w], lane, ti);
#pragma unroll
    for (int q = 0; q < 4; ++q) {
      int j = lane + (q << 6);
      rowbuf[w][j * NTn + t] = sb[w][swz(j)].x * scale;
    }
    __syncthreads();
  }
  float* ob = out + ((size_t)(b * Hn + i0) * Wn) * NTn;
  for (int f = threadIdx.x; f < 4 * Wn * NTn; f += 256) {
    int r = f / (Wn * NTn), off = f - r * (Wn * NTn);
    ob[(size_t)r * Wn * NTn + off] = rowbuf[r][off];
  }
}

// ---------------------------------------------------------------------------
extern "C" void kernel_launch(void* const* d_in, const int* in_sizes, int n_in,
                              void* d_out, int out_size, void* d_ws, size_t ws_size,
                              hipStream_t stream) {
  const float* inp = (const float*)d_in[0];
  const float* T   = (const float*)d_in[1];
  float* out = (float*)d_out;
  char* ws = (char*)d_ws;

  size_t off = 0;
  float*   P   = (float*)(ws + off);   off += (size_t)Bn * Cn * HWn * sizeof(float);      // 16.8 MB
  int*     idx = (int*)(ws + off);     off += (size_t)NTn * HWn * sizeof(int);            // 2.4 MB
  float*   nx2 = (float*)(ws + off);   off += 256 * sizeof(float);
  float*   ny2 = (float*)(ws + off);   off += 768 * sizeof(float);
  __half2* Fxh = (__half2*)(ws + off); off += (size_t)Bn * Cn * KF * Hn * sizeof(__half2); // 8.5 MB
  float2*  G   = (float2*)(ws + off);  off += (size_t)NTn * Bn * KF * Hn * sizeof(float2); // 9.5 MB
  __half2* Yh  = (__half2*)(ws + off); off += (size_t)NTn * Bn * Cn * KF * Hn * sizeof(__half2); // 76 MB
  (void)off; (void)ws_size; (void)in_sizes; (void)n_in; (void)out_size;

  k_idx<<<(NTn * HWn + 255) / 256, 256, 0, stream>>>(T, idx, nx2, ny2);
  k_transpose<<<Bn * HWn / 16, 256, 0, stream>>>(inp, P);
  k_xrow<<<Bn * Cn * Hn / 16, 256, 0, stream>>>(P, Fxh, nx2);
  k_colfft_h<<<Bn * Cn * KF / 4, 256, 0, stream>>>(Fxh);
  k_yrow<<<NTn * Bn * Cn * Hn / 16, 256, 0, stream>>>(P, idx, Yh, ny2);
  k_ycol<<<NTn * Bn * KF / 4, 256, 0, stream>>>(Yh, Fxh, nx2, ny2, G);
  k_irow<<<Bn * Hn / 4, 256, 0, stream>>>(G, out);
}